// Round 6
// baseline (183.256 us; speedup 1.0000x reference)
//
#include <hip/hip_runtime.h>
#include <math.h>

#define BB 4
#define NN 5
#define CC_DIM 64
#define HH 100
#define WW 252
#define HW (HH * WW)
#define TH 25            // output rows per tile
#define NT (HH / TH)     // 4 tiles
#define PAD 12           // staging window margin (rows)
#define MAXR (TH + 2 * PAD + 1)  // 50 staged rows max
#define PITCH 256        // LDS row pitch in floats (1024 B, bank-aligned)

__global__ __launch_bounds__(256) void where2comm_fuse_kernel(
    const float* __restrict__ x,    // (B*N, C, H, W)
    const float* __restrict__ ptm,  // (B, N, N, 2, 3)
    float* __restrict__ out)        // (B, C, H, W) + 1 scalar
{
    __shared__ float smem[MAXR * PITCH];   // 50 KiB

    const int bi = blockIdx.x;            // b*CC_DIM*NT + c*NT + tile
    const int tile = bi % NT;
    const int c = (bi / NT) % CC_DIM;
    const int b = bi / (NT * CC_DIM);

    const int h0 = tile * TH;
    const int lo = (h0 - PAD > 0) ? (h0 - PAD) : 0;           // first staged row
    const int hi = (h0 + TH + PAD < HH - 1) ? (h0 + TH + PAD) : (HH - 1); // last staged row
    const int nrows = hi - lo + 1;                            // <= 50

    const int tid = threadIdx.x;
    const int lane = tid & 63;
    const int wv = tid >> 6;   // wave id 0..3
    const int w = tid;         // output column; threads 252..255 idle in compute

    // per-thread constant
    const float gx = (2.0f * (float)w + 1.0f) / (float)WW - 1.0f;
    const float gy0 = (2.0f * (float)h0 + 1.0f) / (float)HH - 1.0f;

    const float* th_b = ptm + (size_t)b * (NN * NN * 6);  // theta[b,0,n,:,:]

    float acc[TH];
#pragma unroll
    for (int r = 0; r < TH; ++r) acc[r] = -INFINITY;

    for (int n = 0; n < NN; ++n) {
        const size_t plane_f = ((size_t)(b * NN + n) * CC_DIM + c) * HW;

        // ---- stage rows [lo, hi] of this plane into LDS (streaming, coalesced) ----
        // each wave handles rows wv, wv+4, ... ; 63 lanes x 16B = 1008 B = one row
        for (int r = wv; r < nrows; r += 4) {
            const float* src = x + plane_f + (size_t)(lo + r) * WW + lane * 4;
            if (lane < 63) {
                __builtin_amdgcn_global_load_lds(
                    (const __attribute__((address_space(1))) void*)src,
                    (__attribute__((address_space(3))) void*)(smem + r * PITCH),
                    16, 0, 0);
            }
        }
        asm volatile("s_waitcnt vmcnt(0)" ::: "memory");
        __syncthreads();

        // ---- consume: bilinear gather from LDS, fmax into acc ----
        if (w < WW) {
            const float t00 = th_b[n * 6 + 0];
            const float t01 = th_b[n * 6 + 1];
            const float t02 = th_b[n * 6 + 2];
            const float t10 = th_b[n * 6 + 3];
            const float t11 = th_b[n * 6 + 4];
            const float t12 = th_b[n * 6 + 5];

            const float cx0 = fmaf(t00, gx, t02);  // + t01*gy per row
            const float cy0 = fmaf(t10, gx, t12);
            const float* plane = x + plane_f;

#pragma unroll
            for (int r = 0; r < TH; ++r) {
                const float gyr = fmaf((float)(2 * r), 0.01f, gy0);
                const float cx = fmaf(t01, gyr, cx0);
                const float cy = fmaf(t11, gyr, cy0);
                const float ix = fmaf(cx, 126.0f, 125.5f);   // ((cx+1)*W-1)*0.5
                const float iy = fmaf(cy, 50.0f, 49.5f);     // ((cy+1)*H-1)*0.5

                const float x0f = floorf(ix);
                const float y0f = floorf(iy);
                const float x1f = x0f + 1.0f;
                const float y1f = y0f + 1.0f;

                const float wx1 = ix - x0f;
                const float wx0 = 1.0f - wx1;
                const float wy1 = iy - y0f;
                const float wy0 = 1.0f - wy1;

                const float mx0 = (x0f >= 0.0f && x0f <= (float)(WW - 1)) ? 1.0f : 0.0f;
                const float mx1 = (x1f >= 0.0f && x1f <= (float)(WW - 1)) ? 1.0f : 0.0f;
                const float my0 = (y0f >= 0.0f && y0f <= (float)(HH - 1)) ? 1.0f : 0.0f;
                const float my1 = (y1f >= 0.0f && y1f <= (float)(HH - 1)) ? 1.0f : 0.0f;

                const float e00 = wx0 * wy0 * mx0 * my0;
                const float e10 = wx1 * wy0 * mx1 * my0;
                const float e01 = wx0 * wy1 * mx0 * my1;
                const float e11 = wx1 * wy1 * mx1 * my1;

                const int xi0 = (int)fminf(fmaxf(x0f, 0.0f), (float)(WW - 1));
                const int xi1 = (int)fminf(fmaxf(x1f, 0.0f), (float)(WW - 1));
                const int yi0 = (int)fminf(fmaxf(y0f, 0.0f), (float)(HH - 1));
                const int yi1 = (int)fminf(fmaxf(y1f, 0.0f), (float)(HH - 1));

                const int cl = (int)fminf(fmaxf(x0f, 0.0f), (float)(WW - 2));
                const int rl = (int)fminf(fmaxf(y0f, 0.0f), (float)(HH - 2));

                // route corner weights to the 2x2 patch at (rl, cl); OOB corners weight 0
                const float sx0 = (float)(xi0 - cl);
                const float sx1 = (float)(xi1 - cl);
                const float sy0 = (float)(yi0 - rl);
                const float sy1 = (float)(yi1 - rl);
                const float nx0 = 1.0f - sx0, nx1 = 1.0f - sx1;
                const float ny0 = 1.0f - sy0, ny1 = 1.0f - sy1;

                const float g00 = e00 * nx0 * ny0 + e10 * nx1 * ny0 + e01 * nx0 * ny1 + e11 * nx1 * ny1;
                const float g01 = e00 * sx0 * ny0 + e10 * sx1 * ny0 + e01 * sx0 * ny1 + e11 * sx1 * ny1;
                const float g10 = e00 * nx0 * sy0 + e10 * nx1 * sy0 + e01 * nx0 * sy1 + e11 * nx1 * sy1;
                const float g11 = e00 * sx0 * sy0 + e10 * sx1 * sy0 + e01 * sx0 * sy1 + e11 * sx1 * sy1;

                float l00, l01, l10, l11;
                if (rl >= lo && rl + 1 <= hi) {
                    const float* sp = smem + (rl - lo) * PITCH + cl;
                    l00 = sp[0];
                    l01 = sp[1];
                    l10 = sp[PITCH];
                    l11 = sp[PITCH + 1];
                } else {
                    // rare fallback: sample outside staged window (correct for any theta)
                    const float* gp = plane + (size_t)rl * WW + cl;
                    l00 = gp[0];
                    l01 = gp[1];
                    l10 = gp[WW];
                    l11 = gp[WW + 1];
                }

                float v = l00 * g00;
                v = fmaf(l01, g01, v);
                v = fmaf(l10, g10, v);
                v = fmaf(l11, g11, v);
                acc[r] = fmaxf(acc[r], v);
            }
        }
        __syncthreads();   // protect LDS before next agent's staging
    }

    // ---- write tile outputs: out[b, c, h0+r, w] ----
    if (w < WW) {
#pragma unroll
        for (int r = 0; r < TH; ++r) {
            out[((size_t)(b * CC_DIM + c) * HH + h0 + r) * WW + w] = acc[r];
        }
    }

    if (bi == 0 && tid == 0) {
        out[(size_t)BB * CC_DIM * HW] = 0.0f;  // communication_rates
    }
}

extern "C" void kernel_launch(void* const* d_in, const int* in_sizes, int n_in,
                              void* d_out, int out_size, void* d_ws, size_t ws_size,
                              hipStream_t stream) {
    const float* x = (const float*)d_in[0];
    const float* ptm = (const float*)d_in[3];
    float* out = (float*)d_out;

    const int grid = BB * CC_DIM * NT;  // 1024 blocks
    where2comm_fuse_kernel<<<grid, 256, 0, stream>>>(x, ptm, out);
}

// Round 7
// 148.810 us; speedup vs baseline: 1.2315x; 1.2315x over previous
//
#include <hip/hip_runtime.h>
#include <math.h>

#define BB 4
#define NN 5
#define CC_DIM 64
#define HH 100
#define WW 252
#define HW (HH * WW)
#define CPT 4                 // channels per thread
#define NCC (CC_DIM / CPT)    // 16 channel groups
#define TT 5                  // output rows walked per thread (register carry)
#define NTILE (HH / TT)       // 20 row tiles

__global__ __launch_bounds__(256) void where2comm_fuse_kernel(
    const float* __restrict__ x,    // (B*N, C, H, W)
    const float* __restrict__ ptm,  // (B, N, N, 2, 3)
    float* __restrict__ out)        // (B, C, H, W) + 1 scalar
{
    const int bi = blockIdx.x;
    const int tile = bi % NTILE;
    const int cc = (bi / NTILE) % NCC;
    const int b = bi / (NTILE * NCC);

    const int h0 = tile * TT;
    const int c0 = cc * CPT;
    const int w = threadIdx.x;          // lanes = columns (252 active)

    if (w < WW) {
        const float gx = (2.0f * (float)w + 1.0f) / (float)WW - 1.0f;

        // row grid coords for this tile (match reference formula exactly)
        float gys[TT];
#pragma unroll
        for (int r = 0; r < TT; ++r) {
            gys[r] = (2.0f * (float)(h0 + r) + 1.0f) / (float)HH - 1.0f;
        }

        const float* th_b = ptm + (size_t)b * (NN * NN * 6);  // theta[b,0,n,:,:]

        float acc[CPT][TT];
#pragma unroll
        for (int c = 0; c < CPT; ++c) {
#pragma unroll
            for (int r = 0; r < TT; ++r) acc[c][r] = -INFINITY;
        }

#pragma unroll
        for (int n = 0; n < NN; ++n) {
            const float t00 = th_b[n * 6 + 0];
            const float t01 = th_b[n * 6 + 1];
            const float t02 = th_b[n * 6 + 2];
            const float t10 = th_b[n * 6 + 3];
            const float t11 = th_b[n * 6 + 4];
            const float t12 = th_b[n * 6 + 5];

            // per-agent channel-0 plane
            const float* plane = x + ((size_t)(b * NN + n) * CC_DIM + c0) * HW;

            // register-carried 2x2 patch per channel, origin (carry_rl, carry_cl)
            float lo[CPT][2], hi[CPT][2];
            int carry_rl = -1000, carry_cl = -1000;

#pragma unroll
            for (int r = 0; r < TT; ++r) {
                const float gyr = gys[r];
                const float cx = t00 * gx + t01 * gyr + t02;
                const float cy = t10 * gx + t11 * gyr + t12;
                const float ix = ((cx + 1.0f) * (float)WW - 1.0f) * 0.5f;
                const float iy = ((cy + 1.0f) * (float)HH - 1.0f) * 0.5f;

                const float x0f = floorf(ix);
                const float y0f = floorf(iy);
                const float x1f = x0f + 1.0f;
                const float y1f = y0f + 1.0f;

                const float wx1 = ix - x0f;
                const float wx0 = 1.0f - wx1;
                const float wy1 = iy - y0f;
                const float wy0 = 1.0f - wy1;

                // validity (zero-padding semantics)
                const float mx0 = (x0f >= 0.0f && x0f <= (float)(WW - 1)) ? 1.0f : 0.0f;
                const float mx1 = (x1f >= 0.0f && x1f <= (float)(WW - 1)) ? 1.0f : 0.0f;
                const float my0 = (y0f >= 0.0f && y0f <= (float)(HH - 1)) ? 1.0f : 0.0f;
                const float my1 = (y1f >= 0.0f && y1f <= (float)(HH - 1)) ? 1.0f : 0.0f;

                const float e00 = wx0 * wy0 * mx0 * my0;
                const float e10 = wx1 * wy0 * mx1 * my0;
                const float e01 = wx0 * wy1 * mx0 * my1;
                const float e11 = wx1 * wy1 * mx1 * my1;

                // clamped corner indices (reference semantics)
                const int xi0 = (int)fminf(fmaxf(x0f, 0.0f), (float)(WW - 1));
                const int xi1 = (int)fminf(fmaxf(x1f, 0.0f), (float)(WW - 1));
                const int yi0 = (int)fminf(fmaxf(y0f, 0.0f), (float)(HH - 1));
                const int yi1 = (int)fminf(fmaxf(y1f, 0.0f), (float)(HH - 1));

                // in-bounds 2x2 patch origin
                const int cl = (int)fminf(fmaxf(x0f, 0.0f), (float)(WW - 2));
                const int rl = (int)fminf(fmaxf(y0f, 0.0f), (float)(HH - 2));

                // route corner weights to patch elements (OOB corners weight 0)
                const float sx0 = (float)(xi0 - cl);
                const float sx1 = (float)(xi1 - cl);
                const float sy0 = (float)(yi0 - rl);
                const float sy1 = (float)(yi1 - rl);
                const float nx0 = 1.0f - sx0, nx1 = 1.0f - sx1;
                const float ny0 = 1.0f - sy0, ny1 = 1.0f - sy1;

                const float g00 = e00 * nx0 * ny0 + e10 * nx1 * ny0 + e01 * nx0 * ny1 + e11 * nx1 * ny1;
                const float g01 = e00 * sx0 * ny0 + e10 * sx1 * ny0 + e01 * sx0 * ny1 + e11 * sx1 * ny1;
                const float g10 = e00 * nx0 * sy0 + e10 * nx1 * sy0 + e01 * nx0 * sy1 + e11 * nx1 * sy1;
                const float g11 = e00 * sx0 * sy0 + e10 * sx1 * sy0 + e01 * sx0 * sy1 + e11 * sx1 * sy1;

                // ---- register-carry patch update ----
                const int off = rl * WW + cl;
                const bool same  = (rl == carry_rl) && (cl == carry_cl);
                const bool shift = (rl == carry_rl + 1) && (cl == carry_cl);
                if (!same) {
                    if (shift) {
                        // rows advance by 1: old hi becomes lo, load one new row
#pragma unroll
                        for (int c = 0; c < CPT; ++c) {
                            lo[c][0] = hi[c][0];
                            lo[c][1] = hi[c][1];
                            __builtin_memcpy(&hi[c][0], plane + (size_t)c * HW + off + WW, 8);
                        }
                    } else {
                        // full reload (first row of tile, or rare jump)
#pragma unroll
                        for (int c = 0; c < CPT; ++c) {
                            __builtin_memcpy(&lo[c][0], plane + (size_t)c * HW + off, 8);
                            __builtin_memcpy(&hi[c][0], plane + (size_t)c * HW + off + WW, 8);
                        }
                    }
                }
                carry_rl = rl;
                carry_cl = cl;

                // ---- consume ----
#pragma unroll
                for (int c = 0; c < CPT; ++c) {
                    float v = lo[c][0] * g00;
                    v = fmaf(lo[c][1], g01, v);
                    v = fmaf(hi[c][0], g10, v);
                    v = fmaf(hi[c][1], g11, v);
                    acc[c][r] = fmaxf(acc[c][r], v);
                }
            }
        }

        // ---- write outputs: out[b, c0+c, h0+r, w] ----
#pragma unroll
        for (int c = 0; c < CPT; ++c) {
#pragma unroll
            for (int r = 0; r < TT; ++r) {
                out[((size_t)(b * CC_DIM + c0 + c) * HH + h0 + r) * WW + w] = acc[c][r];
            }
        }
    }

    if (bi == 0 && threadIdx.x == 0) {
        out[(size_t)BB * CC_DIM * HW] = 0.0f;  // communication_rates
    }
}

extern "C" void kernel_launch(void* const* d_in, const int* in_sizes, int n_in,
                              void* d_out, int out_size, void* d_ws, size_t ws_size,
                              hipStream_t stream) {
    const float* x = (const float*)d_in[0];
    const float* ptm = (const float*)d_in[3];
    float* out = (float*)d_out;

    const int grid = BB * NCC * NTILE;  // 1280 blocks
    where2comm_fuse_kernel<<<grid, 256, 0, stream>>>(x, ptm, out);
}

// Round 8
// 80.470 us; speedup vs baseline: 2.2773x; 1.8493x over previous
//
#include <hip/hip_runtime.h>
#include <math.h>

#define BB 4
#define NN 5
#define CC_DIM 64
#define HH 100
#define WW 252
#define HW (HH * WW)
#define CPT 8              // channels per thread
#define NCHUNK (CC_DIM / CPT)  // 8 chunks
#define HP (HH / 2)        // 50 row-pairs

__global__ __launch_bounds__(256) void where2comm_fuse_kernel(
    const float* __restrict__ x,    // (B*N, C, H, W)
    const float* __restrict__ ptm,  // (B, N, N, 2, 3)
    float* __restrict__ out)        // (B, C, H, W) + 1 scalar
{
    const int idx = blockIdx.x * blockDim.x + threadIdx.x;
    // total = BB * NCHUNK * HP * WW = 403200, grid exact

    // decompose: w fastest, then row-pair, then channel-chunk, then b
    int w = idx % WW;
    int t = idx / WW;
    int hp = t % HP;
    t /= HP;
    int cc = t % NCHUNK;
    int b = t / NCHUNK;

    const int h0 = 2 * hp;
    const int h1 = h0 + 1;

    const float gx = (2.0f * (float)w + 1.0f) / (float)WW - 1.0f;
    const float gy0 = (2.0f * (float)h0 + 1.0f) / (float)HH - 1.0f;
    const float gy1 = (2.0f * (float)h1 + 1.0f) / (float)HH - 1.0f;

    const float* th_b = ptm + (size_t)b * (NN * NN * 6);  // theta[b,0,n,:,:]

    float acc0[CPT], acc1[CPT];
#pragma unroll
    for (int c = 0; c < CPT; ++c) { acc0[c] = -INFINITY; acc1[c] = -INFINITY; }

#pragma unroll
    for (int n = 0; n < NN; ++n) {
        const float t00 = th_b[n * 6 + 0];
        const float t01 = th_b[n * 6 + 1];
        const float t02 = th_b[n * 6 + 2];
        const float t10 = th_b[n * 6 + 3];
        const float t11 = th_b[n * 6 + 4];
        const float t12 = th_b[n * 6 + 5];

        // ---- geometry for both output rows (reference formulas) ----
        int clA, rlA, clB, rlB;
        float gA00, gA01, gA10, gA11, gB00, gB01, gB10, gB11;

#define GEOM(GY, CL, RL, G00, G01, G10, G11)                                   \
        {                                                                      \
            const float cx = t00 * gx + t01 * (GY) + t02;                      \
            const float cy = t10 * gx + t11 * (GY) + t12;                      \
            const float ix = ((cx + 1.0f) * (float)WW - 1.0f) * 0.5f;          \
            const float iy = ((cy + 1.0f) * (float)HH - 1.0f) * 0.5f;          \
            const float x0f = floorf(ix);                                      \
            const float y0f = floorf(iy);                                      \
            const float x1f = x0f + 1.0f;                                      \
            const float y1f = y0f + 1.0f;                                      \
            const float wx1 = ix - x0f;                                        \
            const float wx0 = 1.0f - wx1;                                      \
            const float wy1 = iy - y0f;                                        \
            const float wy0 = 1.0f - wy1;                                      \
            const float mx0 = (x0f >= 0.0f && x0f <= (float)(WW - 1)) ? 1.0f : 0.0f; \
            const float mx1 = (x1f >= 0.0f && x1f <= (float)(WW - 1)) ? 1.0f : 0.0f; \
            const float my0 = (y0f >= 0.0f && y0f <= (float)(HH - 1)) ? 1.0f : 0.0f; \
            const float my1 = (y1f >= 0.0f && y1f <= (float)(HH - 1)) ? 1.0f : 0.0f; \
            const float e00 = wx0 * wy0 * mx0 * my0;                           \
            const float e10 = wx1 * wy0 * mx1 * my0;                           \
            const float e01 = wx0 * wy1 * mx0 * my1;                           \
            const float e11 = wx1 * wy1 * mx1 * my1;                           \
            const int xi0 = (int)fminf(fmaxf(x0f, 0.0f), (float)(WW - 1));     \
            const int xi1 = (int)fminf(fmaxf(x1f, 0.0f), (float)(WW - 1));     \
            const int yi0 = (int)fminf(fmaxf(y0f, 0.0f), (float)(HH - 1));     \
            const int yi1 = (int)fminf(fmaxf(y1f, 0.0f), (float)(HH - 1));     \
            CL = (int)fminf(fmaxf(x0f, 0.0f), (float)(WW - 2));                \
            RL = (int)fminf(fmaxf(y0f, 0.0f), (float)(HH - 2));                \
            const float sx0 = (float)(xi0 - CL);                               \
            const float sx1 = (float)(xi1 - CL);                               \
            const float sy0 = (float)(yi0 - RL);                               \
            const float sy1 = (float)(yi1 - RL);                               \
            const float nx0 = 1.0f - sx0, nx1 = 1.0f - sx1;                    \
            const float ny0 = 1.0f - sy0, ny1 = 1.0f - sy1;                    \
            G00 = e00 * nx0 * ny0 + e10 * nx1 * ny0 + e01 * nx0 * ny1 + e11 * nx1 * ny1; \
            G01 = e00 * sx0 * ny0 + e10 * sx1 * ny0 + e01 * sx0 * ny1 + e11 * sx1 * ny1; \
            G10 = e00 * nx0 * sy0 + e10 * nx1 * sy0 + e01 * nx0 * sy1 + e11 * nx1 * sy1; \
            G11 = e00 * sx0 * sy0 + e10 * sx1 * sy0 + e01 * sx0 * sy1 + e11 * sx1 * sy1; \
        }

        GEOM(gy0, clA, rlA, gA00, gA01, gA10, gA11)
        GEOM(gy1, clB, rlB, gB00, gB01, gB10, gB11)
#undef GEOM

        const float* plane = x + ((size_t)(b * NN + n) * CC_DIM + cc * CPT) * HW;
        const int offA = rlA * WW + clA;
        const int offB = rlB * WW + clB;

        // ---- load row-pair patch for h0 (batched: 16 dwordx2 in flight) ----
        float L0[CPT][2], L1[CPT][2];
#pragma unroll
        for (int c = 0; c < CPT; ++c) {
            const float* pc = plane + (size_t)c * HW + offA;
            __builtin_memcpy(&L0[c][0], pc, 8);
            __builtin_memcpy(&L1[c][0], pc + WW, 8);
        }

        // ---- consume h0 ----
#pragma unroll
        for (int c = 0; c < CPT; ++c) {
            float v = L0[c][0] * gA00;
            v = fmaf(L0[c][1], gA01, v);
            v = fmaf(L1[c][0], gA10, v);
            v = fmaf(L1[c][1], gA11, v);
            acc0[c] = fmaxf(acc0[c], v);
        }

        // ---- select/load patch for h1, reusing registers when possible ----
        const bool sameCol = (clB == clA);
        const bool reuse0 = sameCol && (rlB == rlA);      // P=L0, Q=L1 (0 loads)
        const bool reuse1 = sameCol && (rlB == rlA + 1);  // P=L1, Q=new  (8 loads)

        float P[CPT][2], Q[CPT][2];
        if (reuse0) {
#pragma unroll
            for (int c = 0; c < CPT; ++c) {
                P[c][0] = L0[c][0]; P[c][1] = L0[c][1];
                Q[c][0] = L1[c][0]; Q[c][1] = L1[c][1];
            }
        } else if (reuse1) {
#pragma unroll
            for (int c = 0; c < CPT; ++c) {
                P[c][0] = L1[c][0]; P[c][1] = L1[c][1];
                __builtin_memcpy(&Q[c][0], plane + (size_t)c * HW + offB + WW, 8);
            }
        } else {
#pragma unroll
            for (int c = 0; c < CPT; ++c) {
                const float* pc = plane + (size_t)c * HW + offB;
                __builtin_memcpy(&P[c][0], pc, 8);
                __builtin_memcpy(&Q[c][0], pc + WW, 8);
            }
        }

        // ---- consume h1 ----
#pragma unroll
        for (int c = 0; c < CPT; ++c) {
            float v = P[c][0] * gB00;
            v = fmaf(P[c][1], gB01, v);
            v = fmaf(Q[c][0], gB10, v);
            v = fmaf(Q[c][1], gB11, v);
            acc1[c] = fmaxf(acc1[c], v);
        }
    }

    // ---- write outputs: out[b, cc*CPT + c, h0/h1, w] ----
#pragma unroll
    for (int c = 0; c < CPT; ++c) {
        const size_t rowbase = ((size_t)(b * CC_DIM + cc * CPT + c) * HH + h0) * WW + w;
        out[rowbase] = acc0[c];
        out[rowbase + WW] = acc1[c];
    }

    if (idx == 0) {
        out[(size_t)BB * CC_DIM * HW] = 0.0f;  // communication_rates
    }
}

extern "C" void kernel_launch(void* const* d_in, const int* in_sizes, int n_in,
                              void* d_out, int out_size, void* d_ws, size_t ws_size,
                              hipStream_t stream) {
    const float* x = (const float*)d_in[0];
    const float* ptm = (const float*)d_in[3];
    float* out = (float*)d_out;

    const int total = BB * NCHUNK * HP * WW;  // 403200
    const int block = 256;
    const int grid = total / block;           // 1575
    where2comm_fuse_kernel<<<grid, block, 0, stream>>>(x, ptm, out);
}